// Round 1
// baseline (12.931 us; speedup 1.0000x reference)
//
#include <hip/hip_runtime.h>
#include <cmath>

// HybridQNN fused kernel.
//
// Closed form of the 4-qubit circuit (derived + hand-verified):
//   h_w = tanh(x . W1[w] + b1[w])          (only wires 0..3 used)
//   u_w = h_w + qw[0,w]
//   z   = cos(qw[2,0]) * cos(u1)*cos(u2)*cos(u3)
//       - sin(qw[2,0]) * cos(qw[1,0])*cos(qw[1,1]) * sin(u0)*sin(u1)
// Then:
//   t_k = relu(z*W2[k] + b2[k]);  out_j = sum_k t_k*W3[j,k] + b3[j]

#define THREADS 256
#define ITER 4

__global__ __launch_bounds__(THREADS) void qnn_fused(
    const float* __restrict__ x,
    const float* __restrict__ W1, const float* __restrict__ b1,
    const float* __restrict__ qw,
    const float* __restrict__ W2, const float* __restrict__ b2,
    const float* __restrict__ W3, const float* __restrict__ b3,
    float* __restrict__ out, int B)
{
    // ---- uniform parameters (same address across lanes -> L1 broadcast) ----
    float w1[16], bb1[4], q0[4];
#pragma unroll
    for (int j = 0; j < 16; ++j) w1[j] = W1[j];
#pragma unroll
    for (int j = 0; j < 4; ++j) { bb1[j] = b1[j]; q0[j] = qw[j]; }

    float sA, cA;
    __sincosf(qw[8], &sA, &cA);                 // A = qw[2,0]
    const float k1 = sA * __cosf(qw[4]) * __cosf(qw[5]);  // sinA*cosB0*cosB1

    float w2[4], bb2[4], w3a[4], w3b[4];
#pragma unroll
    for (int j = 0; j < 4; ++j) {
        w2[j]  = W2[j];  bb2[j] = b2[j];
        w3a[j] = W3[j];  w3b[j] = W3[4 + j];
    }
    const float b30 = b3[0], b31 = b3[1];

    const int base   = blockIdx.x * THREADS + threadIdx.x;
    const int stride = gridDim.x * THREADS;

#pragma unroll
    for (int it = 0; it < ITER; ++it) {
        const int i = base + it * stride;
        if (i < B) {
            const float4 xv = reinterpret_cast<const float4*>(x)[i];

            float u[4];
#pragma unroll
            for (int w = 0; w < 4; ++w) {
                float acc = bb1[w];
                acc = fmaf(xv.x, w1[4 * w + 0], acc);
                acc = fmaf(xv.y, w1[4 * w + 1], acc);
                acc = fmaf(xv.z, w1[4 * w + 2], acc);
                acc = fmaf(xv.w, w1[4 * w + 3], acc);
                // fast, overflow-safe tanh: sign(acc)*(1 - 2/(e^{2|acc|}+1))
                const float e  = __expf(2.0f * fabsf(acc));
                float t        = 1.0f - 2.0f * __builtin_amdgcn_rcpf(e + 1.0f);
                t              = copysignf(t, acc);
                u[w] = t + q0[w];
            }

            const float s0 = __sinf(u[0]);
            float s1, c1;
            __sincosf(u[1], &s1, &c1);
            const float c2v = __cosf(u[2]);
            const float c3v = __cosf(u[3]);

            const float z = cA * c1 * c2v * c3v - k1 * s0 * s1;

            float o0 = b30, o1 = b31;
#pragma unroll
            for (int k = 0; k < 4; ++k) {
                const float t2 = fmaxf(fmaf(z, w2[k], bb2[k]), 0.0f);
                o0 = fmaf(t2, w3a[k], o0);
                o1 = fmaf(t2, w3b[k], o1);
            }
            reinterpret_cast<float2*>(out)[i] = make_float2(o0, o1);
        }
    }
}

extern "C" void kernel_launch(void* const* d_in, const int* in_sizes, int n_in,
                              void* d_out, int out_size, void* d_ws, size_t ws_size,
                              hipStream_t stream) {
    const float* x  = (const float*)d_in[0];
    const float* W1 = (const float*)d_in[1];
    const float* b1 = (const float*)d_in[2];
    const float* qw = (const float*)d_in[3];
    const float* W2 = (const float*)d_in[4];
    const float* b2 = (const float*)d_in[5];
    const float* W3 = (const float*)d_in[6];
    const float* b3 = (const float*)d_in[7];
    float* out = (float*)d_out;

    const int B = in_sizes[0] / 4;
    const int per_block = THREADS * ITER;
    const int blocks = (B + per_block - 1) / per_block;

    qnn_fused<<<blocks, THREADS, 0, stream>>>(x, W1, b1, qw, W2, b2, W3, b3, out, B);
}

// Round 2
// 10.414 us; speedup vs baseline: 1.2417x; 1.2417x over previous
//
#include <hip/hip_runtime.h>
#include <cmath>

// HybridQNN fused kernel — closed form of the 4-qubit circuit:
//   h_w = tanh(x . W1[w] + b1[w])          (only wires 0..3 used)
//   u_w = h_w + qw[0,w]
//   z   = cos(qw[2,0]) * cos(u1)*cos(u2)*cos(u3)
//       - sin(qw[2,0]) * cos(qw[1,0])*cos(qw[1,1]) * sin(u0)*sin(u1)
//   t_k = relu(z*W2[k] + b2[k]);  out_j = sum_k t_k*W3[j,k] + b3[j]
//
// R1: 2 samples/thread (float4 store), 2048 blocks (8/CU) for latency hiding.

#define THREADS 256

__device__ __forceinline__ void sample_out(
    const float4 xv,
    const float* w1, const float* bb1, const float* q0,
    float cA, float k1,
    const float* w2, const float* bb2, const float* w3a, const float* w3b,
    float b30, float b31, float& o0, float& o1)
{
    float u[4];
#pragma unroll
    for (int w = 0; w < 4; ++w) {
        float acc = bb1[w];
        acc = fmaf(xv.x, w1[4 * w + 0], acc);
        acc = fmaf(xv.y, w1[4 * w + 1], acc);
        acc = fmaf(xv.z, w1[4 * w + 2], acc);
        acc = fmaf(xv.w, w1[4 * w + 3], acc);
        // overflow-safe fast tanh: sign(acc)*(1 - 2/(e^{2|acc|}+1))
        const float e = __expf(2.0f * fabsf(acc));
        float t       = 1.0f - 2.0f * __builtin_amdgcn_rcpf(e + 1.0f);
        t             = copysignf(t, acc);
        u[w] = t + q0[w];
    }

    const float s0 = __sinf(u[0]);
    float s1, c1;
    __sincosf(u[1], &s1, &c1);
    const float c2v = __cosf(u[2]);
    const float c3v = __cosf(u[3]);

    const float z = cA * c1 * c2v * c3v - k1 * s0 * s1;

    o0 = b30; o1 = b31;
#pragma unroll
    for (int k = 0; k < 4; ++k) {
        const float t2 = fmaxf(fmaf(z, w2[k], bb2[k]), 0.0f);
        o0 = fmaf(t2, w3a[k], o0);
        o1 = fmaf(t2, w3b[k], o1);
    }
}

__global__ __launch_bounds__(THREADS) void qnn_fused(
    const float* __restrict__ x,
    const float* __restrict__ W1, const float* __restrict__ b1,
    const float* __restrict__ qw,
    const float* __restrict__ W2, const float* __restrict__ b2,
    const float* __restrict__ W3, const float* __restrict__ b3,
    float* __restrict__ out, int B)
{
    // ---- uniform parameters (uniform addresses -> scalar loads) ----
    float w1[16], bb1[4], q0[4];
#pragma unroll
    for (int j = 0; j < 16; ++j) w1[j] = W1[j];
#pragma unroll
    for (int j = 0; j < 4; ++j) { bb1[j] = b1[j]; q0[j] = qw[j]; }

    float sA, cA;
    __sincosf(qw[8], &sA, &cA);                           // A = qw[2,0]
    const float k1 = sA * __cosf(qw[4]) * __cosf(qw[5]);  // sinA*cosB0*cosB1

    float w2[4], bb2[4], w3a[4], w3b[4];
#pragma unroll
    for (int j = 0; j < 4; ++j) {
        w2[j]  = W2[j];  bb2[j] = b2[j];
        w3a[j] = W3[j];  w3b[j] = W3[4 + j];
    }
    const float b30 = b3[0], b31 = b3[1];

    const int pair = blockIdx.x * THREADS + threadIdx.x;   // 2 samples per thread
    const int i0 = pair * 2;
    if (i0 + 1 < B) {
        const float4 xa = reinterpret_cast<const float4*>(x)[i0];
        const float4 xb = reinterpret_cast<const float4*>(x)[i0 + 1];
        float4 o;
        sample_out(xa, w1, bb1, q0, cA, k1, w2, bb2, w3a, w3b, b30, b31, o.x, o.y);
        sample_out(xb, w1, bb1, q0, cA, k1, w2, bb2, w3a, w3b, b30, b31, o.z, o.w);
        reinterpret_cast<float4*>(out)[pair] = o;
    } else if (i0 < B) {  // odd-B tail
        const float4 xa = reinterpret_cast<const float4*>(x)[i0];
        float o0, o1;
        sample_out(xa, w1, bb1, q0, cA, k1, w2, bb2, w3a, w3b, b30, b31, o0, o1);
        reinterpret_cast<float2*>(out)[i0] = make_float2(o0, o1);
    }
}

extern "C" void kernel_launch(void* const* d_in, const int* in_sizes, int n_in,
                              void* d_out, int out_size, void* d_ws, size_t ws_size,
                              hipStream_t stream) {
    const float* x  = (const float*)d_in[0];
    const float* W1 = (const float*)d_in[1];
    const float* b1 = (const float*)d_in[2];
    const float* qw = (const float*)d_in[3];
    const float* W2 = (const float*)d_in[4];
    const float* b2 = (const float*)d_in[5];
    const float* W3 = (const float*)d_in[6];
    const float* b3 = (const float*)d_in[7];
    float* out = (float*)d_out;

    const int B = in_sizes[0] / 4;
    const int per_block = THREADS * 2;
    const int blocks = (B + per_block - 1) / per_block;

    qnn_fused<<<blocks, THREADS, 0, stream>>>(x, W1, b1, qw, W2, b2, W3, b3, out, B);
}

// Round 3
// 9.950 us; speedup vs baseline: 1.2996x; 1.0466x over previous
//
#include <hip/hip_runtime.h>
#include <cmath>

// HybridQNN fused kernel — closed form of the 4-qubit circuit:
//   h_w = tanh(x . W1[w] + b1[w])          (only wires 0..3 used)
//   u_w = h_w + qw[0,w]
//   z   = cos(qw[2,0]) * cos(u1)*cos(u2)*cos(u3)
//       - sin(qw[2,0]) * cos(qw[1,0])*cos(qw[1,1]) * sin(u0)*sin(u1)
//   t_k = relu(z*W2[k] + b2[k]);  out_j = sum_k t_k*W3[j,k] + b3[j]
//
// R1: 2 samples/thread (float4 store), 2048 blocks (8/CU, max occupancy).
// R2: nontemporal float4 store (bypass cache fill on the 8 MB write stream).

#define THREADS 256

typedef float f32x4 __attribute__((ext_vector_type(4)));

__device__ __forceinline__ void sample_out(
    const float4 xv,
    const float* w1, const float* bb1, const float* q0,
    float cA, float k1,
    const float* w2, const float* bb2, const float* w3a, const float* w3b,
    float b30, float b31, float& o0, float& o1)
{
    float u[4];
#pragma unroll
    for (int w = 0; w < 4; ++w) {
        float acc = bb1[w];
        acc = fmaf(xv.x, w1[4 * w + 0], acc);
        acc = fmaf(xv.y, w1[4 * w + 1], acc);
        acc = fmaf(xv.z, w1[4 * w + 2], acc);
        acc = fmaf(xv.w, w1[4 * w + 3], acc);
        // overflow-safe fast tanh: sign(acc)*(1 - 2/(e^{2|acc|}+1))
        const float e = __expf(2.0f * fabsf(acc));
        float t       = 1.0f - 2.0f * __builtin_amdgcn_rcpf(e + 1.0f);
        t             = copysignf(t, acc);
        u[w] = t + q0[w];
    }

    const float s0 = __sinf(u[0]);
    float s1, c1;
    __sincosf(u[1], &s1, &c1);
    const float c2v = __cosf(u[2]);
    const float c3v = __cosf(u[3]);

    const float z = cA * c1 * c2v * c3v - k1 * s0 * s1;

    o0 = b30; o1 = b31;
#pragma unroll
    for (int k = 0; k < 4; ++k) {
        const float t2 = fmaxf(fmaf(z, w2[k], bb2[k]), 0.0f);
        o0 = fmaf(t2, w3a[k], o0);
        o1 = fmaf(t2, w3b[k], o1);
    }
}

__global__ __launch_bounds__(THREADS) void qnn_fused(
    const float* __restrict__ x,
    const float* __restrict__ W1, const float* __restrict__ b1,
    const float* __restrict__ qw,
    const float* __restrict__ W2, const float* __restrict__ b2,
    const float* __restrict__ W3, const float* __restrict__ b3,
    float* __restrict__ out, int B)
{
    // ---- uniform parameters (uniform addresses -> scalar loads) ----
    float w1[16], bb1[4], q0[4];
#pragma unroll
    for (int j = 0; j < 16; ++j) w1[j] = W1[j];
#pragma unroll
    for (int j = 0; j < 4; ++j) { bb1[j] = b1[j]; q0[j] = qw[j]; }

    float sA, cA;
    __sincosf(qw[8], &sA, &cA);                           // A = qw[2,0]
    const float k1 = sA * __cosf(qw[4]) * __cosf(qw[5]);  // sinA*cosB0*cosB1

    float w2[4], bb2[4], w3a[4], w3b[4];
#pragma unroll
    for (int j = 0; j < 4; ++j) {
        w2[j]  = W2[j];  bb2[j] = b2[j];
        w3a[j] = W3[j];  w3b[j] = W3[4 + j];
    }
    const float b30 = b3[0], b31 = b3[1];

    const int pair = blockIdx.x * THREADS + threadIdx.x;   // 2 samples per thread
    const int i0 = pair * 2;
    if (i0 + 1 < B) {
        const float4 xa = reinterpret_cast<const float4*>(x)[i0];
        const float4 xb = reinterpret_cast<const float4*>(x)[i0 + 1];
        f32x4 o;
        float oa0, oa1, ob0, ob1;
        sample_out(xa, w1, bb1, q0, cA, k1, w2, bb2, w3a, w3b, b30, b31, oa0, oa1);
        sample_out(xb, w1, bb1, q0, cA, k1, w2, bb2, w3a, w3b, b30, b31, ob0, ob1);
        o.x = oa0; o.y = oa1; o.z = ob0; o.w = ob1;
        __builtin_nontemporal_store(o, reinterpret_cast<f32x4*>(out) + pair);
    } else if (i0 < B) {  // odd-B tail
        const float4 xa = reinterpret_cast<const float4*>(x)[i0];
        float o0, o1;
        sample_out(xa, w1, bb1, q0, cA, k1, w2, bb2, w3a, w3b, b30, b31, o0, o1);
        reinterpret_cast<float2*>(out)[i0] = make_float2(o0, o1);
    }
}

extern "C" void kernel_launch(void* const* d_in, const int* in_sizes, int n_in,
                              void* d_out, int out_size, void* d_ws, size_t ws_size,
                              hipStream_t stream) {
    const float* x  = (const float*)d_in[0];
    const float* W1 = (const float*)d_in[1];
    const float* b1 = (const float*)d_in[2];
    const float* qw = (const float*)d_in[3];
    const float* W2 = (const float*)d_in[4];
    const float* b2 = (const float*)d_in[5];
    const float* W3 = (const float*)d_in[6];
    const float* b3 = (const float*)d_in[7];
    float* out = (float*)d_out;

    const int B = in_sizes[0] / 4;
    const int per_block = THREADS * 2;
    const int blocks = (B + per_block - 1) / per_block;

    qnn_fused<<<blocks, THREADS, 0, stream>>>(x, W1, b1, qw, W2, b2, W3, b3, out, B);
}